// Round 5
// baseline (263.611 us; speedup 1.0000x reference)
//
#include <hip/hip_runtime.h>
#include <math.h>

#define NA 400000
#define NM 4
#define NP 512
#define ND 32
#define SQF 1.6986437f              /* sqrt(2*log2(e)) folded into BOTH operand scalings */
#define NBH 391                     /* ceil(NA/1024) hist/scatter windows */
#define GTPB 512                    /* gpr threads (8 waves) */
#define NBLK 1024                   /* gpr grid: 4 blocks/CU target */
#define ACUT 60.0f                  /* skip exp when whole 16x64 strip < 2^-60 */

typedef __attribute__((ext_vector_type(8))) __bf16 bf16x8;
typedef __attribute__((ext_vector_type(8))) unsigned short us8;
typedef __attribute__((ext_vector_type(4))) float f32x4;

/* ---- workspace layout (bytes) ---- */
#define WS_ZHI  0                   /* ushort[NM][32][512] = 131072  hi fragments (LDS-staged) */
#define WS_ZLO  131072              /* ushort[NM][32][512] = 131072  lo fragments (L2-read)    */
#define WS_AZ   262144              /* float2[NM*512] = 16384  (alpha, -0.5*||zhat||^2)        */
#define WS_PART 278528              /* int[NBH][4] = 6256 window histogram partials            */
#define WS_CNT  284784              /* int[4] model totals  */
#define WS_CUR  284800              /* int[4] steal cursors */
#define WS_BKT  284816              /* int[NA] = 1.6 MB     */

static __device__ __forceinline__ unsigned short rne_bf16(float f) {
    unsigned u = __builtin_bit_cast(unsigned, f);
    return (unsigned short)((u + 0x7fffu + ((u >> 16) & 1u)) >> 16);
}

// ---------------- K1: Z-prep (blocks 0..3) + window histogram (blocks 4..) ----------------
__global__ void prep_hist_kernel(const float* __restrict__ Z,
                                 const float* __restrict__ alpha,
                                 const float* __restrict__ lls,
                                 const int* __restrict__ el,
                                 unsigned short* __restrict__ zhi,
                                 unsigned short* __restrict__ zlo,
                                 float2* __restrict__ az,
                                 int* __restrict__ part)
{
    __shared__ float isl_s[ND];
    __shared__ int h[16][NM];
    int tid = threadIdx.x;
    if (blockIdx.x < NM) {
        int m = blockIdx.x;
        if (tid < ND) isl_s[tid] = expf(-0.5f * lls[m * ND + tid]) * SQF;
        __syncthreads();
        for (int p = tid; p < NP; p += blockDim.x) {
            const float* zp = Z + (size_t)(m * NP + p) * ND;
            int t = p >> 4, pl = p & 15;
            size_t fb = (size_t)(m * 32 + t) * 512;
            float z2 = 0.f;
#pragma unroll
            for (int d = 0; d < ND; ++d) {
                float zs = zp[d] * isl_s[d];
                unsigned u  = __builtin_bit_cast(unsigned, zs);
                unsigned hu = u & 0xffff0000u;
                float hif   = __builtin_bit_cast(float, hu);
                unsigned short lo = rne_bf16(zs - hif);
                float zr = hif + __builtin_bit_cast(float, (unsigned)lo << 16);
                z2 = fmaf(zr, zr, z2);
                int lane = pl + 16 * (d >> 3), j = d & 7;    // A-frag order
                zhi[fb + lane * 8 + j] = (unsigned short)(hu >> 16);
                zlo[fb + lane * 8 + j] = lo;
            }
            az[m * NP + p] = make_float2(alpha[m * NP + p], -0.5f * z2);
        }
    } else {
        int wnd = blockIdx.x - NM;
        int wv = tid >> 6, lane = tid & 63;
        int i = wnd * 1024 + tid;
        int e = (i < NA) ? el[i] : -1;
#pragma unroll
        for (int mm = 0; mm < NM; ++mm) {
            unsigned long long b = __ballot(e == mm);
            if (lane == 0) h[wv][mm] = __popcll(b);
        }
        __syncthreads();
        if (tid < NM) {
            int s = 0;
#pragma unroll
            for (int k = 0; k < 16; ++k) s += h[k][tid];
            part[wnd * 4 + tid] = s;
        }
    }
}

// ---------------- K2: scatter with on-the-fly prefix (deterministic, atomic-free) ----------------
__global__ void scatter_kernel(const int* __restrict__ el,
                               const int* __restrict__ part,
                               int* __restrict__ cnt,
                               int* __restrict__ cur,
                               int* __restrict__ bucket)
{
    __shared__ int wcnt_s[16][NM];
    __shared__ int wvoff_s[16][NM];
    __shared__ int gbase_s[NM];
    __shared__ int tot_s[NM];
    __shared__ int bw_s[NM];
    int b = blockIdx.x, tid = threadIdx.x;
    int wv = tid >> 6, lane = tid & 63;
    int i = b * 1024 + tid;
    int e = (i < NA) ? el[i] : -1;
    unsigned long long lt = (1ULL << lane) - 1ULL;
    int myrank = 0;
#pragma unroll
    for (int mm = 0; mm < NM; ++mm) {
        unsigned long long bl = __ballot(e == mm);
        if (e == mm) myrank = __popcll(bl & lt);
        if (lane == 0) wcnt_s[wv][mm] = __popcll(bl);
    }
    if (wv == 0) {                               // totals + exclusive "below" from partials
        int t0 = 0, t1 = 0, t2 = 0, t3 = 0, b0 = 0, b1 = 0, b2 = 0, b3 = 0;
        for (int w2 = lane; w2 < NBH; w2 += 64) {
            int4 pv = ((const int4*)part)[w2];
            t0 += pv.x; t1 += pv.y; t2 += pv.z; t3 += pv.w;
            if (w2 < b) { b0 += pv.x; b1 += pv.y; b2 += pv.z; b3 += pv.w; }
        }
#pragma unroll
        for (int s = 1; s < 64; s <<= 1) {
            t0 += __shfl_xor(t0, s); t1 += __shfl_xor(t1, s);
            t2 += __shfl_xor(t2, s); t3 += __shfl_xor(t3, s);
            b0 += __shfl_xor(b0, s); b1 += __shfl_xor(b1, s);
            b2 += __shfl_xor(b2, s); b3 += __shfl_xor(b3, s);
        }
        if (lane == 0) {
            tot_s[0] = t0; tot_s[1] = t1; tot_s[2] = t2; tot_s[3] = t3;
            bw_s[0] = b0; bw_s[1] = b1; bw_s[2] = b2; bw_s[3] = b3;
        }
    }
    __syncthreads();
    if (tid < NM) {
        int g = bw_s[tid];
        for (int mm = 0; mm < NM; ++mm) if (mm < tid) g += tot_s[mm];
        gbase_s[tid] = g;
        int run = 0;
#pragma unroll
        for (int k = 0; k < 16; ++k) { wvoff_s[k][tid] = run; run += wcnt_s[k][tid]; }
        if (b == 0) { cnt[tid] = tot_s[tid]; cur[tid] = 0; }   // replay-safe re-init
    }
    __syncthreads();
    if (e >= 0) bucket[gbase_s[e] + wvoff_s[wv][e] + myrank] = i;
}

// ---------------- K3: split-bf16 MFMA, folded C-init, exact skip, per-wave stealing ----------------
__global__ __launch_bounds__(GTPB, 8)
void gpr_kernel(const float* __restrict__ x,
                const int* __restrict__ bucket,
                const unsigned short* __restrict__ zhi_w,
                const unsigned short* __restrict__ zlo_w,
                const float2* __restrict__ az_w,
                const float* __restrict__ lls,
                const int* __restrict__ cnt_w,
                int* __restrict__ cur_w,
                float* __restrict__ out)
{
    __shared__ __align__(16) unsigned short zf[32][512];   // 32 KiB (hi fragments)
    __shared__ __align__(16) float2 az_s[NP];              // 4 KiB

    int m = blockIdx.x & 3;
    int tid = threadIdx.x;
    int c0 = cnt_w[0], c1 = cnt_w[1], c2 = cnt_w[2], c3 = cnt_w[3];
    int c    = (m == 0) ? c0 : (m == 1) ? c1 : (m == 2) ? c2 : c3;
    int base = (m == 0) ? 0 : (m == 1) ? c0 : (m == 2) ? c0 + c1 : c0 + c1 + c2;

    {   // stage hi-fragments (32 KiB linear) + az (4 KiB)
        const int4* zg = (const int4*)(zhi_w + (size_t)m * 16384);
        int4* zs = (int4*)&zf[0][0];
#pragma unroll
        for (int i = 0; i < 4; ++i) zs[tid + i * GTPB] = zg[tid + i * GTPB];
        if (tid < 256)
            ((float4*)az_s)[tid] = ((const float4*)(az_w + m * NP))[tid];
    }
    __syncthreads();                             // only barrier

    int lane = tid & 63;
    int lg = lane >> 4, ll = lane & 15;
    int k0 = lg * 8;

    float w[8];
#pragma unroll
    for (int i = 0; i < 8; ++i) w[i] = expf(-0.5f * lls[m * ND + k0 + i]) * SQF;

    const int4* alp = (const int4*)(zlo_w + (size_t)m * 16384) + lane;  // lo frags: alp[t*64]

    for (;;) {
        int s = 0;
        if (lane == 0) s = atomicAdd(cur_w + m, 1);
        s = __shfl(s, 0);
        int wbase = s * 64;
        if (wbase >= c) break;

        us8 Bh[4], Bl[4];
        float x2l[4], acc[4];
#pragma unroll
        for (int nt = 0; nt < 4; ++nt) {
            int j = wbase + nt * 16 + ll;
            int n = bucket[base + ((j < c) ? j : (c - 1))];
            const float4* xp = (const float4*)(x + (size_t)n * ND + k0);
            float4 a = xp[0], b = xp[1];
            float xs[8] = {a.x * w[0], a.y * w[1], a.z * w[2], a.w * w[3],
                           b.x * w[4], b.y * w[5], b.z * w[6], b.w * w[7]};
            float s2 = 0.f;
#pragma unroll
            for (int i = 0; i < 8; ++i) {
                unsigned u  = __builtin_bit_cast(unsigned, xs[i]);
                unsigned hu = u & 0xffff0000u;
                float hif   = __builtin_bit_cast(float, hu);
                float lof   = xs[i] - hif;       // exact residual
                Bh[nt][i] = (unsigned short)(hu >> 16);
                Bl[nt][i] = (unsigned short)(__builtin_bit_cast(unsigned, lof) >> 16);
                s2 = fmaf(xs[i], xs[i], s2);
            }
            s2 += __shfl_xor(s2, 16);
            s2 += __shfl_xor(s2, 32);
            x2l[nt] = 0.5f * s2;
            acc[nt] = 0.f;
        }

        for (int t = 0; t < 32; ++t) {
            bf16x8 Ah = *(const bf16x8*)&zf[t][lane * 8];
            bf16x8 Al = __builtin_bit_cast(bf16x8, alp[t * 64]);
            float4 az01 = *(const float4*)&az_s[t * 16 + 4 * lg];       // (a0,-y0,a1,-y1)
            float4 az23 = *(const float4*)&az_s[t * 16 + 4 * lg + 2];   // (a2,-y2,a3,-y3)
#pragma unroll
            for (int nt = 0; nt < 4; ++nt) {
                bf16x8 bh = __builtin_bit_cast(bf16x8, Bh[nt]);
                bf16x8 bl = __builtin_bit_cast(bf16x8, Bl[nt]);
                float xl = x2l[nt];
                f32x4 d = {az01.y - xl, az01.w - xl, az23.y - xl, az23.w - xl};
                d = __builtin_amdgcn_mfma_f32_16x16x32_bf16(Al, bh, d, 0, 0, 0);
                d = __builtin_amdgcn_mfma_f32_16x16x32_bf16(Ah, bl, d, 0, 0, 0);
                d = __builtin_amdgcn_mfma_f32_16x16x32_bf16(Ah, bh, d, 0, 0, 0);
                float mx = fmaxf(fmaxf(d[0], d[1]), fmaxf(d[2], d[3]));
                if (__any(mx >= -ACUT)) {        // exact per-pair bound, ~74% skip
                    acc[nt] = fmaf(az01.x, __builtin_amdgcn_exp2f(d[0]), acc[nt]);
                    acc[nt] = fmaf(az01.z, __builtin_amdgcn_exp2f(d[1]), acc[nt]);
                    acc[nt] = fmaf(az23.x, __builtin_amdgcn_exp2f(d[2]), acc[nt]);
                    acc[nt] = fmaf(az23.z, __builtin_amdgcn_exp2f(d[3]), acc[nt]);
                }
            }
        }

#pragma unroll
        for (int nt = 0; nt < 4; ++nt) {
            float v = acc[nt];
            v += __shfl_xor(v, 16);
            v += __shfl_xor(v, 32);
            if (lane < 16) {
                int j = wbase + nt * 16 + lane;
                if (j < c) out[bucket[base + j]] = v;
            }
        }
    }
}

// ---------------- launch: 3 dispatches, no memsets ----------------
extern "C" void kernel_launch(void* const* d_in, const int* in_sizes, int n_in,
                              void* d_out, int out_size, void* d_ws, size_t ws_size,
                              hipStream_t stream)
{
    const int*   element    = (const int*)d_in[0];
    const float* x          = (const float*)d_in[1];
    const float* inducing_x = (const float*)d_in[2];
    const float* alpha      = (const float*)d_in[3];
    const float* log_ls     = (const float*)d_in[4];
    float* out = (float*)d_out;

    char* ws = (char*)d_ws;
    unsigned short* zhi = (unsigned short*)(ws + WS_ZHI);
    unsigned short* zlo = (unsigned short*)(ws + WS_ZLO);
    float2* az   = (float2*)(ws + WS_AZ);
    int*    part = (int*)(ws + WS_PART);
    int*    cnt  = (int*)(ws + WS_CNT);
    int*    cur  = (int*)(ws + WS_CUR);
    int*    bkt  = (int*)(ws + WS_BKT);

    (void)in_sizes; (void)n_in; (void)out_size; (void)ws_size;

    prep_hist_kernel<<<NM + NBH, 1024, 0, stream>>>(inducing_x, alpha, log_ls, element,
                                                    zhi, zlo, az, part);
    scatter_kernel<<<NBH, 1024, 0, stream>>>(element, part, cnt, cur, bkt);
    gpr_kernel<<<NBLK, GTPB, 0, stream>>>(x, bkt, zhi, zlo, az, log_ls, cnt, cur, out);
}

// Round 6
// 149.935 us; speedup vs baseline: 1.7582x; 1.7582x over previous
//
#include <hip/hip_runtime.h>
#include <math.h>

#define NA 400000
#define NM 4
#define NP 512
#define ND 32
#define SQF 1.6986437f              /* sqrt(2*log2(e)) folded into BOTH operand scalings */
#define NBH 391                     /* ceil(NA/1024) hist/scatter windows */
#define GTPB 512                    /* gpr threads (8 waves) */
#define NBLK 512                    /* gpr grid: exactly 2 blocks/CU resident */
#define ACUT 60.0f                  /* skip exp when whole 16x64 strip < 2^-60 */

typedef __attribute__((ext_vector_type(8))) __bf16 bf16x8;
typedef __attribute__((ext_vector_type(8))) unsigned short us8;
typedef __attribute__((ext_vector_type(4))) float f32x4;

/* ---- workspace layout (bytes) ---- */
#define WS_ZFRAG 0                  /* ushort[NM][32][2][512] = 262144  (hi|lo interleaved, A-frag order) */
#define WS_AZ    262144             /* float2[NM*512] = 16384  (alpha, -0.5*||zhat||^2) */
#define WS_PART  278528             /* int[NBH][4] = 6256 window histogram partials */
#define WS_CNT   284784             /* int[4] model totals  */
#define WS_CUR   284800             /* int[4] steal cursors */
#define WS_BKT   284816             /* int[NA] = 1.6 MB     */

static __device__ __forceinline__ unsigned short rne_bf16(float f) {
    unsigned u = __builtin_bit_cast(unsigned, f);
    return (unsigned short)((u + 0x7fffu + ((u >> 16) & 1u)) >> 16);
}

// ---------------- K1: Z-prep (blocks 0..3) + window histogram (blocks 4..) ----------------
__global__ void prep_hist_kernel(const float* __restrict__ Z,
                                 const float* __restrict__ alpha,
                                 const float* __restrict__ lls,
                                 const int* __restrict__ el,
                                 unsigned short* __restrict__ zfrag,
                                 float2* __restrict__ az,
                                 int* __restrict__ part)
{
    __shared__ float isl_s[ND];
    __shared__ int h[16][NM];
    int tid = threadIdx.x;
    if (blockIdx.x < NM) {
        int m = blockIdx.x;
        if (tid < ND) isl_s[tid] = expf(-0.5f * lls[m * ND + tid]) * SQF;
        __syncthreads();
        for (int p = tid; p < NP; p += blockDim.x) {
            const float* zp = Z + (size_t)(m * NP + p) * ND;
            int t = p >> 4, pl = p & 15;
            size_t fb = (size_t)(m * 32 + t) * 1024;
            float z2 = 0.f;
#pragma unroll
            for (int d = 0; d < ND; ++d) {
                float zs = zp[d] * isl_s[d];
                unsigned u  = __builtin_bit_cast(unsigned, zs);
                unsigned hu = u & 0xffff0000u;
                float hif   = __builtin_bit_cast(float, hu);
                unsigned short lo = rne_bf16(zs - hif);
                float zr = hif + __builtin_bit_cast(float, (unsigned)lo << 16);
                z2 = fmaf(zr, zr, z2);
                int lane = pl + 16 * (d >> 3), j = d & 7;    // A-frag order
                zfrag[fb +       lane * 8 + j] = (unsigned short)(hu >> 16);
                zfrag[fb + 512 + lane * 8 + j] = lo;
            }
            az[m * NP + p] = make_float2(alpha[m * NP + p], -0.5f * z2);
        }
    } else {
        int wnd = blockIdx.x - NM;
        int wv = tid >> 6, lane = tid & 63;
        int i = wnd * 1024 + tid;
        int e = (i < NA) ? el[i] : -1;
#pragma unroll
        for (int mm = 0; mm < NM; ++mm) {
            unsigned long long b = __ballot(e == mm);
            if (lane == 0) h[wv][mm] = __popcll(b);
        }
        __syncthreads();
        if (tid < NM) {
            int s = 0;
#pragma unroll
            for (int k = 0; k < 16; ++k) s += h[k][tid];
            part[wnd * 4 + tid] = s;
        }
    }
}

// ---------------- K2: scatter with on-the-fly prefix (deterministic, atomic-free) ----------------
__global__ void scatter_kernel(const int* __restrict__ el,
                               const int* __restrict__ part,
                               int* __restrict__ cnt,
                               int* __restrict__ cur,
                               int* __restrict__ bucket)
{
    __shared__ int wcnt_s[16][NM];
    __shared__ int wvoff_s[16][NM];
    __shared__ int gbase_s[NM];
    __shared__ int tot_s[NM];
    __shared__ int bw_s[NM];
    int b = blockIdx.x, tid = threadIdx.x;
    int wv = tid >> 6, lane = tid & 63;
    int i = b * 1024 + tid;
    int e = (i < NA) ? el[i] : -1;
    unsigned long long lt = (1ULL << lane) - 1ULL;
    int myrank = 0;
#pragma unroll
    for (int mm = 0; mm < NM; ++mm) {
        unsigned long long bl = __ballot(e == mm);
        if (e == mm) myrank = __popcll(bl & lt);
        if (lane == 0) wcnt_s[wv][mm] = __popcll(bl);
    }
    if (wv == 0) {                               // totals + exclusive "below" from partials
        int t0 = 0, t1 = 0, t2 = 0, t3 = 0, b0 = 0, b1 = 0, b2 = 0, b3 = 0;
        for (int w2 = lane; w2 < NBH; w2 += 64) {
            int4 pv = ((const int4*)part)[w2];
            t0 += pv.x; t1 += pv.y; t2 += pv.z; t3 += pv.w;
            if (w2 < b) { b0 += pv.x; b1 += pv.y; b2 += pv.z; b3 += pv.w; }
        }
#pragma unroll
        for (int s = 1; s < 64; s <<= 1) {
            t0 += __shfl_xor(t0, s); t1 += __shfl_xor(t1, s);
            t2 += __shfl_xor(t2, s); t3 += __shfl_xor(t3, s);
            b0 += __shfl_xor(b0, s); b1 += __shfl_xor(b1, s);
            b2 += __shfl_xor(b2, s); b3 += __shfl_xor(b3, s);
        }
        if (lane == 0) {
            tot_s[0] = t0; tot_s[1] = t1; tot_s[2] = t2; tot_s[3] = t3;
            bw_s[0] = b0; bw_s[1] = b1; bw_s[2] = b2; bw_s[3] = b3;
        }
    }
    __syncthreads();
    if (tid < NM) {
        int g = bw_s[tid];
        for (int mm = 0; mm < NM; ++mm) if (mm < tid) g += tot_s[mm];
        gbase_s[tid] = g;
        int run = 0;
#pragma unroll
        for (int k = 0; k < 16; ++k) { wvoff_s[k][tid] = run; run += wcnt_s[k][tid]; }
        if (b == 0) { cnt[tid] = tot_s[tid]; cur[tid] = 0; }   // replay-safe re-init
    }
    __syncthreads();
    if (e >= 0) bucket[gbase_s[e] + wvoff_s[wv][e] + myrank] = i;
}

// ---------------- K3: round-4 body (no spill) + per-wave work-stealing ----------------
__global__ __launch_bounds__(GTPB, 4)
void gpr_kernel(const float* __restrict__ x,
                const int* __restrict__ bucket,
                const unsigned short* __restrict__ zfrag_w,
                const float2* __restrict__ az_w,
                const float* __restrict__ lls,
                const int* __restrict__ cnt_w,
                int* __restrict__ cur_w,
                float* __restrict__ out)
{
    __shared__ __align__(16) unsigned short zf[32][2][512];   // 64 KiB (hi|lo interleaved)
    __shared__ __align__(16) float2 az_s[NP];                 // 4 KiB

    int m = blockIdx.x & 3;
    int tid = threadIdx.x;
    int c0 = cnt_w[0], c1 = cnt_w[1], c2 = cnt_w[2], c3 = cnt_w[3];
    int c    = (m == 0) ? c0 : (m == 1) ? c1 : (m == 2) ? c2 : c3;
    int base = (m == 0) ? 0 : (m == 1) ? c0 : (m == 2) ? c0 + c1 : c0 + c1 + c2;

    {   // stage this model's Z fragments (64 KiB linear) + az (4 KiB)
        const int4* zg = (const int4*)(zfrag_w + (size_t)m * 32768);
        int4* zs = (int4*)&zf[0][0][0];
#pragma unroll
        for (int i = 0; i < 8; ++i) zs[tid + i * GTPB] = zg[tid + i * GTPB];
        if (tid < 256)
            ((float4*)az_s)[tid] = ((const float4*)(az_w + m * NP))[tid];
    }
    __syncthreads();                             // only barrier

    int lane = tid & 63;
    int lg = lane >> 4, ll = lane & 15;
    int k0 = lg * 8;

    float w[8];
#pragma unroll
    for (int i = 0; i < 8; ++i) w[i] = expf(-0.5f * lls[m * ND + k0 + i]) * SQF;

    for (;;) {
        int s = 0;
        if (lane == 0) s = atomicAdd(cur_w + m, 1);
        s = __shfl(s, 0);
        int wbase = s * 64;
        if (wbase >= c) break;

        us8 Bh[4], Bl[4];
        float x2l[4], acc[4];
#pragma unroll
        for (int nt = 0; nt < 4; ++nt) {
            int j = wbase + nt * 16 + ll;
            int n = bucket[base + ((j < c) ? j : (c - 1))];
            const float4* xp = (const float4*)(x + (size_t)n * ND + k0);
            float4 a = xp[0], b = xp[1];
            float xs[8] = {a.x * w[0], a.y * w[1], a.z * w[2], a.w * w[3],
                           b.x * w[4], b.y * w[5], b.z * w[6], b.w * w[7]};
            float s2 = 0.f;
#pragma unroll
            for (int i = 0; i < 8; ++i) {
                unsigned u  = __builtin_bit_cast(unsigned, xs[i]);
                unsigned hu = u & 0xffff0000u;
                float hif   = __builtin_bit_cast(float, hu);
                float lof   = xs[i] - hif;       // exact residual
                Bh[nt][i] = (unsigned short)(hu >> 16);
                Bl[nt][i] = (unsigned short)(__builtin_bit_cast(unsigned, lof) >> 16);
                s2 = fmaf(xs[i], xs[i], s2);
            }
            s2 += __shfl_xor(s2, 16);
            s2 += __shfl_xor(s2, 32);
            x2l[nt] = 0.5f * s2;
            acc[nt] = 0.f;
        }

#pragma unroll 2
        for (int t = 0; t < 32; ++t) {
            bf16x8 Ah = *(const bf16x8*)&zf[t][0][lane * 8];
            bf16x8 Al = *(const bf16x8*)&zf[t][1][lane * 8];
            float4 az01 = *(const float4*)&az_s[t * 16 + 4 * lg];       // (a0,-y0,a1,-y1)
            float4 az23 = *(const float4*)&az_s[t * 16 + 4 * lg + 2];   // (a2,-y2,a3,-y3)
#pragma unroll
            for (int nt = 0; nt < 4; ++nt) {
                bf16x8 bh = __builtin_bit_cast(bf16x8, Bh[nt]);
                bf16x8 bl = __builtin_bit_cast(bf16x8, Bl[nt]);
                float xl = x2l[nt];
                f32x4 d = {az01.y - xl, az01.w - xl, az23.y - xl, az23.w - xl};
                d = __builtin_amdgcn_mfma_f32_16x16x32_bf16(Al, bh, d, 0, 0, 0);
                d = __builtin_amdgcn_mfma_f32_16x16x32_bf16(Ah, bl, d, 0, 0, 0);
                d = __builtin_amdgcn_mfma_f32_16x16x32_bf16(Ah, bh, d, 0, 0, 0);
                float mx = fmaxf(fmaxf(d[0], d[1]), fmaxf(d[2], d[3]));
                if (__any(mx >= -ACUT)) {        // exact per-pair bound, ~74% skip
                    acc[nt] = fmaf(az01.x, __builtin_amdgcn_exp2f(d[0]), acc[nt]);
                    acc[nt] = fmaf(az01.z, __builtin_amdgcn_exp2f(d[1]), acc[nt]);
                    acc[nt] = fmaf(az23.x, __builtin_amdgcn_exp2f(d[2]), acc[nt]);
                    acc[nt] = fmaf(az23.z, __builtin_amdgcn_exp2f(d[3]), acc[nt]);
                }
            }
        }

#pragma unroll
        for (int nt = 0; nt < 4; ++nt) {
            float v = acc[nt];
            v += __shfl_xor(v, 16);
            v += __shfl_xor(v, 32);
            if (lane < 16) {
                int j = wbase + nt * 16 + lane;
                if (j < c) out[bucket[base + j]] = v;
            }
        }
    }
}

// ---------------- launch: 3 dispatches, no memsets ----------------
extern "C" void kernel_launch(void* const* d_in, const int* in_sizes, int n_in,
                              void* d_out, int out_size, void* d_ws, size_t ws_size,
                              hipStream_t stream)
{
    const int*   element    = (const int*)d_in[0];
    const float* x          = (const float*)d_in[1];
    const float* inducing_x = (const float*)d_in[2];
    const float* alpha      = (const float*)d_in[3];
    const float* log_ls     = (const float*)d_in[4];
    float* out = (float*)d_out;

    char* ws = (char*)d_ws;
    unsigned short* zfrag = (unsigned short*)(ws + WS_ZFRAG);
    float2* az   = (float2*)(ws + WS_AZ);
    int*    part = (int*)(ws + WS_PART);
    int*    cnt  = (int*)(ws + WS_CNT);
    int*    cur  = (int*)(ws + WS_CUR);
    int*    bkt  = (int*)(ws + WS_BKT);

    (void)in_sizes; (void)n_in; (void)out_size; (void)ws_size;

    prep_hist_kernel<<<NM + NBH, 1024, 0, stream>>>(inducing_x, alpha, log_ls, element,
                                                    zfrag, az, part);
    scatter_kernel<<<NBH, 1024, 0, stream>>>(element, part, cnt, cur, bkt);
    gpr_kernel<<<NBLK, GTPB, 0, stream>>>(x, bkt, zfrag, az, log_ls, cnt, cur, out);
}

// Round 7
// 63.097 us; speedup vs baseline: 4.1779x; 2.3763x over previous
//
#include <hip/hip_runtime.h>
#include <math.h>

#define NA 400000
#define NM 4
#define NP 512
#define ND 32
#define SQF 1.6986437f              /* sqrt(2*log2(e)) folded into BOTH operand scalings */
#define NBH 391                     /* ceil(NA/1024) hist/scatter windows */
#define GTPB 512                    /* gpr threads (8 waves) */
#define NBLK 1024                   /* gpr grid: 4 blocks/CU, 2048 waves per model */
#define WPM ((NBLK / NM) * 8)       /* 2048 waves per model */
#define ACUT 60.0f                  /* skip exp when whole 16x64 strip < 2^-60 */

typedef __attribute__((ext_vector_type(8))) __bf16 bf16x8;
typedef __attribute__((ext_vector_type(8))) unsigned short us8;
typedef __attribute__((ext_vector_type(4))) float f32x4;

/* ---- workspace layout (bytes) ---- */
#define WS_ZHI  0                   /* ushort[NM][32][512] = 131072  hi fragments (LDS-staged) */
#define WS_ZLO  131072              /* ushort[NM][32][512] = 131072  lo fragments (L2-read)    */
#define WS_AZY  262144              /* float[NM*512] = 8192   (-0.5*||zhat||^2, p-order)       */
#define WS_ALP  270336              /* float[NM*512] = 8192   (alpha, p-order)                 */
#define WS_ISL  278528              /* float[NM*32]  = 512    (exp(-ls/2)*SQF)                 */
#define WS_PART 279040              /* int[NBH][4] = 6256 window histogram partials            */
#define WS_CNT  285296              /* int[4] model totals                                     */
#define WS_BKT  285312              /* int[NA] = 1.6 MB                                        */

static __device__ __forceinline__ unsigned short rne_bf16(float f) {
    unsigned u = __builtin_bit_cast(unsigned, f);
    return (unsigned short)((u + 0x7fffu + ((u >> 16) & 1u)) >> 16);
}

// ---------------- K1: Z-prep (blocks 0..3) + window histogram (blocks 4..) ----------------
__global__ void prep_hist_kernel(const float* __restrict__ Z,
                                 const float* __restrict__ alpha,
                                 const float* __restrict__ lls,
                                 const int* __restrict__ el,
                                 unsigned short* __restrict__ zhi,
                                 unsigned short* __restrict__ zlo,
                                 float* __restrict__ azy,
                                 float* __restrict__ alp,
                                 float* __restrict__ isl,
                                 int* __restrict__ part)
{
    __shared__ float isl_s[ND];
    __shared__ int h[16][NM];
    int tid = threadIdx.x;
    if (blockIdx.x < NM) {
        int m = blockIdx.x;
        if (tid < ND) {
            float v = expf(-0.5f * lls[m * ND + tid]) * SQF;
            isl_s[tid] = v;
            isl[m * ND + tid] = v;
        }
        __syncthreads();
        for (int p = tid; p < NP; p += blockDim.x) {
            const float* zp = Z + (size_t)(m * NP + p) * ND;
            int t = p >> 4, pl = p & 15;
            size_t fb = (size_t)(m * 32 + t) * 512;
            float z2 = 0.f;
#pragma unroll
            for (int d = 0; d < ND; ++d) {
                float zs = zp[d] * isl_s[d];
                unsigned u  = __builtin_bit_cast(unsigned, zs);
                unsigned hu = u & 0xffff0000u;
                float hif   = __builtin_bit_cast(float, hu);
                unsigned short lo = rne_bf16(zs - hif);
                float zr = hif + __builtin_bit_cast(float, (unsigned)lo << 16);
                z2 = fmaf(zr, zr, z2);
                int lane = pl + 16 * (d >> 3), j = d & 7;    // A-frag order
                zhi[fb + lane * 8 + j] = (unsigned short)(hu >> 16);
                zlo[fb + lane * 8 + j] = lo;
            }
            azy[m * NP + p] = -0.5f * z2;
            alp[m * NP + p] = alpha[m * NP + p];
        }
    } else {
        int wnd = blockIdx.x - NM;
        int wv = tid >> 6, lane = tid & 63;
        int i = wnd * 1024 + tid;
        int e = (i < NA) ? el[i] : -1;
#pragma unroll
        for (int mm = 0; mm < NM; ++mm) {
            unsigned long long b = __ballot(e == mm);
            if (lane == 0) h[wv][mm] = __popcll(b);
        }
        __syncthreads();
        if (tid < NM) {
            int s = 0;
#pragma unroll
            for (int k = 0; k < 16; ++k) s += h[k][tid];
            part[wnd * 4 + tid] = s;
        }
    }
}

// ---------------- K2: scatter with on-the-fly prefix (deterministic, atomic-free) ----------------
__global__ void scatter_kernel(const int* __restrict__ el,
                               const int* __restrict__ part,
                               int* __restrict__ cnt,
                               int* __restrict__ bucket)
{
    __shared__ int wcnt_s[16][NM];
    __shared__ int wvoff_s[16][NM];
    __shared__ int gbase_s[NM];
    __shared__ int tot_s[NM];
    __shared__ int bw_s[NM];
    int b = blockIdx.x, tid = threadIdx.x;
    int wv = tid >> 6, lane = tid & 63;
    int i = b * 1024 + tid;
    int e = (i < NA) ? el[i] : -1;
    unsigned long long lt = (1ULL << lane) - 1ULL;
    int myrank = 0;
#pragma unroll
    for (int mm = 0; mm < NM; ++mm) {
        unsigned long long bl = __ballot(e == mm);
        if (e == mm) myrank = __popcll(bl & lt);
        if (lane == 0) wcnt_s[wv][mm] = __popcll(bl);
    }
    if (wv == 0) {                               // totals + exclusive "below" from partials
        int t0 = 0, t1 = 0, t2 = 0, t3 = 0, b0 = 0, b1 = 0, b2 = 0, b3 = 0;
        for (int w2 = lane; w2 < NBH; w2 += 64) {
            int4 pv = ((const int4*)part)[w2];
            t0 += pv.x; t1 += pv.y; t2 += pv.z; t3 += pv.w;
            if (w2 < b) { b0 += pv.x; b1 += pv.y; b2 += pv.z; b3 += pv.w; }
        }
#pragma unroll
        for (int s = 1; s < 64; s <<= 1) {
            t0 += __shfl_xor(t0, s); t1 += __shfl_xor(t1, s);
            t2 += __shfl_xor(t2, s); t3 += __shfl_xor(t3, s);
            b0 += __shfl_xor(b0, s); b1 += __shfl_xor(b1, s);
            b2 += __shfl_xor(b2, s); b3 += __shfl_xor(b3, s);
        }
        if (lane == 0) {
            tot_s[0] = t0; tot_s[1] = t1; tot_s[2] = t2; tot_s[3] = t3;
            bw_s[0] = b0; bw_s[1] = b1; bw_s[2] = b2; bw_s[3] = b3;
        }
    }
    __syncthreads();
    if (tid < NM) {
        int g = bw_s[tid];
        for (int mm = 0; mm < NM; ++mm) if (mm < tid) g += tot_s[mm];
        gbase_s[tid] = g;
        int run = 0;
#pragma unroll
        for (int k = 0; k < 16; ++k) { wvoff_s[k][tid] = run; run += wcnt_s[k][tid]; }
        if (b == 0) cnt[tid] = tot_s[tid];       // replay-safe (rewritten every call)
    }
    __syncthreads();
    if (e >= 0) bucket[gbase_s[e] + wvoff_s[wv][e] + myrank] = i;
}

// ---------------- K3: static 1-strip-per-wave, LDS C-init, hi-Z in LDS / lo-Z from L2 ----------------
__global__ __launch_bounds__(GTPB, 4)
void gpr_kernel(const float* __restrict__ x,
                const int* __restrict__ bucket,
                const unsigned short* __restrict__ zhi_w,
                const unsigned short* __restrict__ zlo_w,
                const float* __restrict__ azy_w,
                const float* __restrict__ alp_w,
                const float* __restrict__ isl_w,
                const int* __restrict__ cnt_w,
                float* __restrict__ out)
{
    __shared__ __align__(16) unsigned short zf[32][512];   // 32 KiB (hi fragments)
    __shared__ __align__(16) float azy_s[NP];              // 2 KiB (-0.5*||zhat||^2)
    __shared__ __align__(16) float alp_s[NP];              // 2 KiB (alpha)

    int m = blockIdx.x & 3;
    int tid = threadIdx.x;
    int c0 = cnt_w[0], c1 = cnt_w[1], c2 = cnt_w[2], c3 = cnt_w[3];
    int c    = (m == 0) ? c0 : (m == 1) ? c1 : (m == 2) ? c2 : c3;
    int base = (m == 0) ? 0 : (m == 1) ? c0 : (m == 2) ? c0 + c1 : c0 + c1 + c2;

    {   // stage hi-fragments (32 KiB linear) + azy + alpha (2+2 KiB)
        const int4* zg = (const int4*)(zhi_w + (size_t)m * 16384);
        int4* zs = (int4*)&zf[0][0];
#pragma unroll
        for (int i = 0; i < 4; ++i) zs[tid + i * GTPB] = zg[tid + i * GTPB];
        if (tid < 128)
            ((float4*)azy_s)[tid] = ((const float4*)(azy_w + m * NP))[tid];
        else if (tid < 256)
            ((float4*)alp_s)[tid - 128] = ((const float4*)(alp_w + m * NP))[tid - 128];
    }
    __syncthreads();                             // only barrier

    int wv = tid >> 6, lane = tid & 63;
    int lg = lane >> 4, ll = lane & 15;
    int k0 = lg * 8;
    int wm = (blockIdx.x >> 2) * 8 + wv;         // wave id within model, [0, WPM)

    const float4* wp = (const float4*)(isl_w + m * ND + k0);
    float4 w0 = wp[0], w1 = wp[1];
    const int4* alo = (const int4*)zlo_w + (size_t)m * 2048 + lane;   // lo frags: alo[t*64]

    for (int s = wm; s * 64 < c; s += WPM) {     // static: <=1 iter in practice
        int wbase = s * 64;

        us8 Bh[4], Bl[4];
        float x2l[4], xlc[4], acc[4];
#pragma unroll
        for (int nt = 0; nt < 4; ++nt) {
            int j = wbase + nt * 16 + ll;
            int n = bucket[base + ((j < c) ? j : (c - 1))];
            const float4* xp = (const float4*)(x + (size_t)n * ND + k0);
            float4 a = xp[0], b = xp[1];
            float xs[8] = {a.x * w0.x, a.y * w0.y, a.z * w0.z, a.w * w0.w,
                           b.x * w1.x, b.y * w1.y, b.z * w1.z, b.w * w1.w};
            float s2 = 0.f;
#pragma unroll
            for (int i = 0; i < 8; ++i) {
                unsigned u  = __builtin_bit_cast(unsigned, xs[i]);
                unsigned hu = u & 0xffff0000u;
                float hif   = __builtin_bit_cast(float, hu);
                float lof   = xs[i] - hif;       // exact residual
                Bh[nt][i] = (unsigned short)(hu >> 16);
                Bl[nt][i] = (unsigned short)(__builtin_bit_cast(unsigned, lof) >> 16);
                s2 = fmaf(xs[i], xs[i], s2);
            }
            s2 += __shfl_xor(s2, 16);
            s2 += __shfl_xor(s2, 32);
            x2l[nt] = 0.5f * s2;
            xlc[nt] = x2l[nt] - ACUT;
            acc[nt] = 0.f;
        }

#pragma unroll 2
        for (int t = 0; t < 32; ++t) {
            bf16x8 Ah = *(const bf16x8*)&zf[t][lane * 8];
            bf16x8 Al = __builtin_bit_cast(bf16x8, alo[t * 64]);
            f32x4 dinit = __builtin_bit_cast(f32x4, *(const float4*)&azy_s[t * 16 + 4 * lg]);
#pragma unroll
            for (int nt = 0; nt < 4; ++nt) {
                bf16x8 bh = __builtin_bit_cast(bf16x8, Bh[nt]);
                bf16x8 bl = __builtin_bit_cast(bf16x8, Bl[nt]);
                f32x4 d = dinit;                 // C-init straight from LDS, zero VALU
                d = __builtin_amdgcn_mfma_f32_16x16x32_bf16(Al, bh, d, 0, 0, 0);
                d = __builtin_amdgcn_mfma_f32_16x16x32_bf16(Ah, bl, d, 0, 0, 0);
                d = __builtin_amdgcn_mfma_f32_16x16x32_bf16(Ah, bh, d, 0, 0, 0);
                float mx = fmaxf(fmaxf(d[0], d[1]), fmaxf(d[2], d[3]));
                if (__any(mx >= xlc[nt])) {      // exact per-pair bound, ~74% skip
                    float4 al4 = *(const float4*)&alp_s[t * 16 + 4 * lg];
                    float xl = x2l[nt];
                    acc[nt] = fmaf(al4.x, __builtin_amdgcn_exp2f(d[0] - xl), acc[nt]);
                    acc[nt] = fmaf(al4.y, __builtin_amdgcn_exp2f(d[1] - xl), acc[nt]);
                    acc[nt] = fmaf(al4.z, __builtin_amdgcn_exp2f(d[2] - xl), acc[nt]);
                    acc[nt] = fmaf(al4.w, __builtin_amdgcn_exp2f(d[3] - xl), acc[nt]);
                }
            }
        }

#pragma unroll
        for (int nt = 0; nt < 4; ++nt) {
            float v = acc[nt];
            v += __shfl_xor(v, 16);
            v += __shfl_xor(v, 32);
            if (lane < 16) {
                int j = wbase + nt * 16 + lane;
                if (j < c) out[bucket[base + j]] = v;
            }
        }
    }
}

// ---------------- launch: 3 dispatches, no memsets, no atomics ----------------
extern "C" void kernel_launch(void* const* d_in, const int* in_sizes, int n_in,
                              void* d_out, int out_size, void* d_ws, size_t ws_size,
                              hipStream_t stream)
{
    const int*   element    = (const int*)d_in[0];
    const float* x          = (const float*)d_in[1];
    const float* inducing_x = (const float*)d_in[2];
    const float* alpha      = (const float*)d_in[3];
    const float* log_ls     = (const float*)d_in[4];
    float* out = (float*)d_out;

    char* ws = (char*)d_ws;
    unsigned short* zhi = (unsigned short*)(ws + WS_ZHI);
    unsigned short* zlo = (unsigned short*)(ws + WS_ZLO);
    float* azy  = (float*)(ws + WS_AZY);
    float* alp  = (float*)(ws + WS_ALP);
    float* isl  = (float*)(ws + WS_ISL);
    int*   part = (int*)(ws + WS_PART);
    int*   cnt  = (int*)(ws + WS_CNT);
    int*   bkt  = (int*)(ws + WS_BKT);

    (void)in_sizes; (void)n_in; (void)out_size; (void)ws_size;

    prep_hist_kernel<<<NM + NBH, 1024, 0, stream>>>(inducing_x, alpha, log_ls, element,
                                                    zhi, zlo, azy, alp, isl, part);
    scatter_kernel<<<NBH, 1024, 0, stream>>>(element, part, cnt, bkt);
    gpr_kernel<<<NBLK, GTPB, 0, stream>>>(x, bkt, zhi, zlo, azy, alp, isl, cnt, out);
}

// Round 8
// 59.078 us; speedup vs baseline: 4.4621x; 1.0680x over previous
//
#include <hip/hip_runtime.h>
#include <math.h>

#define NA 400000
#define NM 4
#define NP 512
#define ND 32
#define SQF 1.6986437f              /* sqrt(2*log2(e)) folded into BOTH operand scalings */
#define NBH 391                     /* ceil(NA/1024) hist/scatter windows */
#define GTPB 512                    /* gpr threads (8 waves) */
#define NBLK 1024                   /* gpr grid: 2048 waves per model */
#define WPM ((NBLK / NM) * 8)       /* 2048 waves per model */
#define ACUT 60.0f                  /* skip exp when whole 16x64 strip < 2^-60 */

typedef __attribute__((ext_vector_type(8))) __bf16 bf16x8;
typedef __attribute__((ext_vector_type(8))) unsigned short us8;
typedef __attribute__((ext_vector_type(4))) float f32x4;

/* ---- workspace layout (bytes) ---- */
#define WS_ZHI  0                   /* ushort[NM][32][512] = 131072  hi fragments (LDS-staged) */
#define WS_ZLO  131072              /* ushort[NM][32][512] = 131072  lo fragments (L2-read)    */
#define WS_AZY  262144              /* float[NM*512] = 8192   (-0.5*||zhat||^2, p-order)       */
#define WS_ALP  270336              /* float[NM*512] = 8192   (alpha, p-order)                 */
#define WS_ISL  278528              /* float[NM*32]  = 512    (exp(-ls/2)*SQF)                 */
#define WS_PART 279040              /* int[NBH][4] = 6256 window histogram partials            */
#define WS_CNT  285296              /* int[4] model totals                                     */
#define WS_BKT  285312              /* int[NA] = 1.6 MB                                        */

static __device__ __forceinline__ unsigned short rne_bf16(float f) {
    unsigned u = __builtin_bit_cast(unsigned, f);
    return (unsigned short)((u + 0x7fffu + ((u >> 16) & 1u)) >> 16);
}

// ---------------- K1: Z-prep (blocks 0..3) + window histogram (blocks 4..) ----------------
__global__ void prep_hist_kernel(const float* __restrict__ Z,
                                 const float* __restrict__ alpha,
                                 const float* __restrict__ lls,
                                 const int* __restrict__ el,
                                 unsigned short* __restrict__ zhi,
                                 unsigned short* __restrict__ zlo,
                                 float* __restrict__ azy,
                                 float* __restrict__ alp,
                                 float* __restrict__ isl,
                                 int* __restrict__ part)
{
    __shared__ float isl_s[ND];
    __shared__ int h[16][NM];
    int tid = threadIdx.x;
    if (blockIdx.x < NM) {
        int m = blockIdx.x;
        if (tid < ND) {
            float v = expf(-0.5f * lls[m * ND + tid]) * SQF;
            isl_s[tid] = v;
            isl[m * ND + tid] = v;
        }
        __syncthreads();
        for (int p = tid; p < NP; p += blockDim.x) {
            const float* zp = Z + (size_t)(m * NP + p) * ND;
            int t = p >> 4, pl = p & 15;
            size_t fb = (size_t)(m * 32 + t) * 512;
            float z2 = 0.f;
#pragma unroll
            for (int d = 0; d < ND; ++d) {
                float zs = zp[d] * isl_s[d];
                unsigned u  = __builtin_bit_cast(unsigned, zs);
                unsigned hu = u & 0xffff0000u;
                float hif   = __builtin_bit_cast(float, hu);
                unsigned short lo = rne_bf16(zs - hif);
                float zr = hif + __builtin_bit_cast(float, (unsigned)lo << 16);
                z2 = fmaf(zr, zr, z2);
                int lane = pl + 16 * (d >> 3), j = d & 7;    // A-frag order
                zhi[fb + lane * 8 + j] = (unsigned short)(hu >> 16);
                zlo[fb + lane * 8 + j] = lo;
            }
            azy[m * NP + p] = -0.5f * z2;
            alp[m * NP + p] = alpha[m * NP + p];
        }
    } else {
        int wnd = blockIdx.x - NM;
        int wv = tid >> 6, lane = tid & 63;
        int i = wnd * 1024 + tid;
        int e = (i < NA) ? el[i] : -1;
#pragma unroll
        for (int mm = 0; mm < NM; ++mm) {
            unsigned long long b = __ballot(e == mm);
            if (lane == 0) h[wv][mm] = __popcll(b);
        }
        __syncthreads();
        if (tid < NM) {
            int s = 0;
#pragma unroll
            for (int k = 0; k < 16; ++k) s += h[k][tid];
            part[wnd * 4 + tid] = s;
        }
    }
}

// ---------------- K2: scatter with on-the-fly prefix (deterministic, atomic-free) ----------------
__global__ void scatter_kernel(const int* __restrict__ el,
                               const int* __restrict__ part,
                               int* __restrict__ cnt,
                               int* __restrict__ bucket)
{
    __shared__ int wcnt_s[16][NM];
    __shared__ int wvoff_s[16][NM];
    __shared__ int gbase_s[NM];
    __shared__ int tot_s[NM];
    __shared__ int bw_s[NM];
    int b = blockIdx.x, tid = threadIdx.x;
    int wv = tid >> 6, lane = tid & 63;
    int i = b * 1024 + tid;
    int e = (i < NA) ? el[i] : -1;
    unsigned long long lt = (1ULL << lane) - 1ULL;
    int myrank = 0;
#pragma unroll
    for (int mm = 0; mm < NM; ++mm) {
        unsigned long long bl = __ballot(e == mm);
        if (e == mm) myrank = __popcll(bl & lt);
        if (lane == 0) wcnt_s[wv][mm] = __popcll(bl);
    }
    if (wv == 0) {                               // totals + exclusive "below" from partials
        int t0 = 0, t1 = 0, t2 = 0, t3 = 0, b0 = 0, b1 = 0, b2 = 0, b3 = 0;
        for (int w2 = lane; w2 < NBH; w2 += 64) {
            int4 pv = ((const int4*)part)[w2];
            t0 += pv.x; t1 += pv.y; t2 += pv.z; t3 += pv.w;
            if (w2 < b) { b0 += pv.x; b1 += pv.y; b2 += pv.z; b3 += pv.w; }
        }
#pragma unroll
        for (int s = 1; s < 64; s <<= 1) {
            t0 += __shfl_xor(t0, s); t1 += __shfl_xor(t1, s);
            t2 += __shfl_xor(t2, s); t3 += __shfl_xor(t3, s);
            b0 += __shfl_xor(b0, s); b1 += __shfl_xor(b1, s);
            b2 += __shfl_xor(b2, s); b3 += __shfl_xor(b3, s);
        }
        if (lane == 0) {
            tot_s[0] = t0; tot_s[1] = t1; tot_s[2] = t2; tot_s[3] = t3;
            bw_s[0] = b0; bw_s[1] = b1; bw_s[2] = b2; bw_s[3] = b3;
        }
    }
    __syncthreads();
    if (tid < NM) {
        int g = bw_s[tid];
        for (int mm = 0; mm < NM; ++mm) if (mm < tid) g += tot_s[mm];
        gbase_s[tid] = g;
        int run = 0;
#pragma unroll
        for (int k = 0; k < 16; ++k) { wvoff_s[k][tid] = run; run += wcnt_s[k][tid]; }
        if (b == 0) cnt[tid] = tot_s[tid];       // replay-safe (rewritten every call)
    }
    __syncthreads();
    if (e >= 0) bucket[gbase_s[e] + wvoff_s[wv][e] + myrank] = i;
}

// ---------------- frag build helper (gather 64 atoms -> B fragments) ----------------
static __device__ __forceinline__ void build_frags(
    const float* __restrict__ x, const int* __restrict__ bucket,
    int base, int c, int wbase, int ll, int k0, float4 w0, float4 w1,
    us8* Bh, us8* Bl, float* x2l)
{
#pragma unroll
    for (int nt = 0; nt < 4; ++nt) {
        int j = wbase + nt * 16 + ll;
        int n = bucket[base + ((j < c) ? j : (c - 1))];
        const float4* xp = (const float4*)(x + (size_t)n * ND + k0);
        float4 a = xp[0], b = xp[1];
        float xs[8] = {a.x * w0.x, a.y * w0.y, a.z * w0.z, a.w * w0.w,
                       b.x * w1.x, b.y * w1.y, b.z * w1.z, b.w * w1.w};
        float s2 = 0.f;
#pragma unroll
        for (int i = 0; i < 8; ++i) {
            unsigned u  = __builtin_bit_cast(unsigned, xs[i]);
            unsigned hu = u & 0xffff0000u;
            float hif   = __builtin_bit_cast(float, hu);
            float lof   = xs[i] - hif;           // exact residual
            Bh[nt][i] = (unsigned short)(hu >> 16);
            Bl[nt][i] = (unsigned short)(__builtin_bit_cast(unsigned, lof) >> 16);
            s2 = fmaf(xs[i], xs[i], s2);
        }
        s2 += __shfl_xor(s2, 16);
        s2 += __shfl_xor(s2, 32);
        x2l[nt] = 0.5f * s2;
    }
}

// ---------------- K3: batched MFMA issue + rotated prefetch + deferred branch tail ----------------
__global__ __launch_bounds__(GTPB, 4)
void gpr_kernel(const float* __restrict__ x,
                const int* __restrict__ bucket,
                const unsigned short* __restrict__ zhi_w,
                const unsigned short* __restrict__ zlo_w,
                const float* __restrict__ azy_w,
                const float* __restrict__ alp_w,
                const float* __restrict__ isl_w,
                const int* __restrict__ cnt_w,
                float* __restrict__ out)
{
    __shared__ __align__(16) unsigned short zf[32][512];   // 32 KiB (hi fragments)
    __shared__ __align__(16) float azy_s[NP];              // 2 KiB
    __shared__ __align__(16) float alp_s[NP];              // 2 KiB

    int m = blockIdx.x & 3;
    int tid = threadIdx.x;
    int c0 = cnt_w[0], c1 = cnt_w[1], c2 = cnt_w[2], c3 = cnt_w[3];
    int c    = (m == 0) ? c0 : (m == 1) ? c1 : (m == 2) ? c2 : c3;
    int base = (m == 0) ? 0 : (m == 1) ? c0 : (m == 2) ? c0 + c1 : c0 + c1 + c2;

    int wv = tid >> 6, lane = tid & 63;
    int lg = lane >> 4, ll = lane & 15;
    int k0 = lg * 8;
    int wm = (blockIdx.x >> 2) * 8 + wv;         // wave id within model, [0, WPM)

    const float4* wp = (const float4*)(isl_w + m * ND + k0);
    float4 w0 = wp[0], w1 = wp[1];

    {   // stage hi-fragments (32 KiB linear) + azy + alpha (2+2 KiB)
        const int4* zg = (const int4*)(zhi_w + (size_t)m * 16384);
        int4* zs = (int4*)&zf[0][0];
#pragma unroll
        for (int i = 0; i < 4; ++i) zs[tid + i * GTPB] = zg[tid + i * GTPB];
        if (tid < 128)
            ((float4*)azy_s)[tid] = ((const float4*)(azy_w + m * NP))[tid];
        else if (tid < 256)
            ((float4*)alp_s)[tid - 128] = ((const float4*)(alp_w + m * NP))[tid - 128];
    }

    // first strip's gather + frag build BEFORE the barrier (x-latency hides under staging)
    us8 Bh[4], Bl[4];
    float x2l[4];
    bool active = ((size_t)wm * 64 < (size_t)c);
    if (active)
        build_frags(x, bucket, base, c, wm * 64, ll, k0, w0, w1, Bh, Bl, x2l);

    __syncthreads();                             // only barrier

    const int4* alo = (const int4*)zlo_w + (size_t)m * 2048 + lane;   // lo frags: alo[t*64]

    for (int s = wm; s * 64 < c; s += WPM) {     // <=1 iter in practice
        int wbase = s * 64;
        if (s != wm)                             // correctness path only (c > 131072)
            build_frags(x, bucket, base, c, wbase, ll, k0, w0, w1, Bh, Bl, x2l);

        float acc[4] = {0.f, 0.f, 0.f, 0.f};

        // rotated prefetch prologue
        bf16x8 Ah = *(const bf16x8*)&zf[0][lane * 8];
        int4   Alr = alo[0];
        float4 di  = *(const float4*)&azy_s[4 * lg];

#pragma unroll 2
        for (int t = 0; t < 32; ++t) {
            bf16x8 AhC = Ah;
            bf16x8 AlC = __builtin_bit_cast(bf16x8, Alr);
            f32x4 dinit = __builtin_bit_cast(f32x4, di);
            int tn = (t + 1) & 31;               // wraps to 0 on last iter (value unused)
            Ah  = *(const bf16x8*)&zf[tn][lane * 8];
            Alr = alo[tn * 64];
            di  = *(const float4*)&azy_s[tn * 16 + 4 * lg];

            f32x4 dd[4];
            __builtin_amdgcn_s_setprio(1);
#pragma unroll
            for (int nt = 0; nt < 4; ++nt) {     // 12 MFMAs issued back-to-back
                bf16x8 bh = __builtin_bit_cast(bf16x8, Bh[nt]);
                bf16x8 bl = __builtin_bit_cast(bf16x8, Bl[nt]);
                f32x4 d = dinit;
                d = __builtin_amdgcn_mfma_f32_16x16x32_bf16(AlC, bh, d, 0, 0, 0);
                d = __builtin_amdgcn_mfma_f32_16x16x32_bf16(AhC, bl, d, 0, 0, 0);
                d = __builtin_amdgcn_mfma_f32_16x16x32_bf16(AhC, bh, d, 0, 0, 0);
                dd[nt] = d;
            }
            __builtin_amdgcn_s_setprio(0);

#pragma unroll
            for (int nt = 0; nt < 4; ++nt) {     // single drain point, branchy tail after
                f32x4 d = dd[nt];
                float mx = fmaxf(fmaxf(d[0], d[1]), fmaxf(d[2], d[3]));
                if (__any(mx + ACUT >= x2l[nt])) {   // exact per-pair bound, ~74% skip
                    float4 al4 = *(const float4*)&alp_s[t * 16 + 4 * lg];
                    float xl = x2l[nt];
                    acc[nt] = fmaf(al4.x, __builtin_amdgcn_exp2f(d[0] - xl), acc[nt]);
                    acc[nt] = fmaf(al4.y, __builtin_amdgcn_exp2f(d[1] - xl), acc[nt]);
                    acc[nt] = fmaf(al4.z, __builtin_amdgcn_exp2f(d[2] - xl), acc[nt]);
                    acc[nt] = fmaf(al4.w, __builtin_amdgcn_exp2f(d[3] - xl), acc[nt]);
                }
            }
        }

#pragma unroll
        for (int nt = 0; nt < 4; ++nt) {
            float v = acc[nt];
            v += __shfl_xor(v, 16);
            v += __shfl_xor(v, 32);
            if (lane < 16) {
                int j = wbase + nt * 16 + lane;
                if (j < c) out[bucket[base + j]] = v;
            }
        }
    }
}

// ---------------- launch: 3 dispatches, no memsets, no atomics ----------------
extern "C" void kernel_launch(void* const* d_in, const int* in_sizes, int n_in,
                              void* d_out, int out_size, void* d_ws, size_t ws_size,
                              hipStream_t stream)
{
    const int*   element    = (const int*)d_in[0];
    const float* x          = (const float*)d_in[1];
    const float* inducing_x = (const float*)d_in[2];
    const float* alpha      = (const float*)d_in[3];
    const float* log_ls     = (const float*)d_in[4];
    float* out = (float*)d_out;

    char* ws = (char*)d_ws;
    unsigned short* zhi = (unsigned short*)(ws + WS_ZHI);
    unsigned short* zlo = (unsigned short*)(ws + WS_ZLO);
    float* azy  = (float*)(ws + WS_AZY);
    float* alp  = (float*)(ws + WS_ALP);
    float* isl  = (float*)(ws + WS_ISL);
    int*   part = (int*)(ws + WS_PART);
    int*   cnt  = (int*)(ws + WS_CNT);
    int*   bkt  = (int*)(ws + WS_BKT);

    (void)in_sizes; (void)n_in; (void)out_size; (void)ws_size;

    prep_hist_kernel<<<NM + NBH, 1024, 0, stream>>>(inducing_x, alpha, log_ls, element,
                                                    zhi, zlo, azy, alp, isl, part);
    scatter_kernel<<<NBH, 1024, 0, stream>>>(element, part, cnt, bkt);
    gpr_kernel<<<NBLK, GTPB, 0, stream>>>(x, bkt, zhi, zlo, azy, alp, isl, cnt, out);
}